// Round 8
// baseline (513.824 us; speedup 1.0000x reference)
//
#include <hip/hip_runtime.h>
#include <hip/hip_bf16.h>
#include <cstdint>
#include <cmath>

// ---------------------------------------------------------------------------
// Quantized TSRNet forward — bit-faithful emulation of the np FLOAT64
// reference (the harness's comparison target):
//   - s64 = (f64)absmax(w) / 7.0            (absmax of fp32 values is exact)
//   - k   = clip(rint_f64(w / s64), -7, 7)  (exact int levels, half-to-even)
//   - effective weight value = fl64(k * s64) (np's per-element product)
//   - activations after each quant_relu are exact 4-bit int levels
//     (act_scales = 1.0; scale folded into f64 epilogues)
//   - conv2..5/fc: ONE exact int32 dot4 accumulation per output;
//     epilogue y = ((f64)acc * s64) * sa_in + bias, quant in f64.
//     Deviation from np: ~1e-16 relative (accumulation-order only).
//   - conv1: f64 accumulation of (f64)x * fl64(k*s64).
//   - fc2 + quant_identity + softmax fully in f64, cast to fp32 at store.
// ---------------------------------------------------------------------------

#if defined(__has_builtin)
#if __has_builtin(__builtin_amdgcn_sdot4)
#define HAVE_SDOT4 1
#endif
#endif

__device__ __forceinline__ int dot4(unsigned int a, unsigned int b, int c) {
#ifdef HAVE_SDOT4
    return __builtin_amdgcn_sdot4((int)a, (int)b, c, false);
#else
    #pragma unroll
    for (int k = 0; k < 4; ++k) {
        int av = (int)(signed char)((a >> (8 * k)) & 0xffu);
        int bv = (int)(signed char)((b >> (8 * k)) & 0xffu);
        c += av * bv;
    }
    return c;
#endif
}

__device__ __forceinline__ int dot16(uint4 a, uint4 b, int c) {
    c = dot4(a.x, b.x, c);
    c = dot4(a.y, b.y, c);
    c = dot4(a.z, b.z, c);
    c = dot4(a.w, b.w, c);
    return c;
}

// ---------------------------------------------------------------------------
// absmax per weight tensor; scales[t] = absmax (fp32, exact)
// ---------------------------------------------------------------------------
__global__ __launch_bounds__(256) void absmax_part_kernel(
    const float* __restrict__ w1, const float* __restrict__ w2,
    const float* __restrict__ w3, const float* __restrict__ w4,
    const float* __restrict__ w5, const float* __restrict__ wf1,
    const float* __restrict__ wf2, float* __restrict__ partial)
{
    const int t = blockIdx.x >> 5;
    const int k = blockIdx.x & 31;
    const float* p; int n;
    switch (t) {
        case 0: p = w1;  n = 432;    break;
        case 1: p = w2;  n = 4608;   break;
        case 2: p = w3;  n = 18432;  break;
        case 3: p = w4;  n = 73728;  break;
        case 4: p = w5;  n = 294912; break;
        case 5: p = wf1; n = 131072; break;
        default: p = wf2; n = 22016; break;
    }
    float m = 0.f;
    for (int i = k * 256 + threadIdx.x; i < n; i += 32 * 256)
        m = fmaxf(m, fabsf(p[i]));
    #pragma unroll
    for (int off = 32; off; off >>= 1) m = fmaxf(m, __shfl_xor(m, off));
    __shared__ float red[4];
    if ((threadIdx.x & 63) == 0) red[threadIdx.x >> 6] = m;
    __syncthreads();
    if (threadIdx.x == 0) {
        m = fmaxf(fmaxf(red[0], red[1]), fmaxf(red[2], red[3]));
        partial[blockIdx.x] = m;
    }
}

__global__ __launch_bounds__(64) void absmax_final_kernel(
    const float* __restrict__ partial, float* __restrict__ scales)
{
    const int t = blockIdx.x;
    float m = (threadIdx.x < 32) ? partial[t * 32 + threadIdx.x] : 0.f;
    #pragma unroll
    for (int off = 32; off; off >>= 1) m = fmaxf(m, __shfl_xor(m, off));
    if (threadIdx.x == 0) scales[t] = m;   // absmax; consumers divide by 7 in f64
}

// quantize conv weight OIHW -> OHWI int8 levels (f64 round-half-even, np-exact)
template<int CO, int CI>
__global__ __launch_bounds__(256) void qconvw_kernel(
    const float* __restrict__ w, int8_t* __restrict__ qk,
    const float* __restrict__ scales, int sidx)
{
    const double s = (double)scales[sidx] / 7.0;
    const int total = CO * CI * 9;
    int i = blockIdx.x * 256 + threadIdx.x;
    if (i >= total) return;
    int kw = i % 3, kh = (i / 3) % 3, ci = (i / 9) % CI, co = i / (9 * CI);
    double kf = (s > 0.0) ? fmin(fmax(rint((double)w[i] / s), -7.0), 7.0) : 0.0;
    qk[((co * 3 + kh) * 3 + kw) * CI + ci] = (int8_t)kf;
}

__global__ __launch_bounds__(256) void qfcw_kernel(
    const float* __restrict__ w, int8_t* __restrict__ qk,
    const float* __restrict__ scales, int sidx, int total)
{
    const double s = (double)scales[sidx] / 7.0;
    int i = blockIdx.x * 256 + threadIdx.x;
    if (i >= total) return;
    double kf = (s > 0.0) ? fmin(fmax(rint((double)w[i] / s), -7.0), 7.0) : 0.0;
    qk[i] = (int8_t)kf;
}

// ---------------------------------------------------------------------------
// Conv1: fp32 (2048,3,32,32) -> f64 acc with fl64(k*s64) weights -> quant_relu
// -> pool -> u8 levels NHWC (2048,16,16,16)
// ---------------------------------------------------------------------------
__global__ __launch_bounds__(256) void conv1_kernel(
    const float* __restrict__ x, const int8_t* __restrict__ qk,
    const float* __restrict__ bias, const float* __restrict__ wscales,
    const float* __restrict__ act_scales, uint8_t* __restrict__ a1)
{
    __shared__ alignas(16) float xin[3 * 34 * 34];
    const int tid = threadIdx.x;
    const int n = blockIdx.x;
    for (int i = tid; i < 3 * 34 * 34; i += 256) xin[i] = 0.f;
    __syncthreads();
    const float* xs = x + (size_t)n * 3072;
    for (int i = tid; i < 3072; i += 256) {
        int c = i >> 10, pix = i & 1023, h = pix >> 5, w = pix & 31;
        xin[c * 1156 + (h + 1) * 34 + (w + 1)] = xs[i];
    }
    __syncthreads();

    const double s64 = (double)wscales[0] / 7.0;
    const double sa = (double)act_scales[0];
    const int co = tid & 15, g = tid >> 4;
    double wr[27];
    #pragma unroll
    for (int k = 0; k < 27; ++k)
        wr[k] = (double)qk[co * 27 + k] * s64;          // fl64(k*s64) = np weight
    const double bco = (double)bias[co];
    uint8_t* outrow = a1 + (size_t)n * 4096;

    for (int t = 0; t < 16; ++t) {
        double acc[2][2] = {{0.0, 0.0}, {0.0, 0.0}};
        #pragma unroll
        for (int ci = 0; ci < 3; ++ci) {
            double xw[4][4];
            #pragma unroll
            for (int rr = 0; rr < 4; ++rr) {
                const int base = ci * 1156 + (2 * t + rr) * 34 + 2 * g;
                float2 v0 = *reinterpret_cast<const float2*>(&xin[base]);
                float2 v1 = *reinterpret_cast<const float2*>(&xin[base + 2]);
                xw[rr][0] = (double)v0.x; xw[rr][1] = (double)v0.y;
                xw[rr][2] = (double)v1.x; xw[rr][3] = (double)v1.y;
            }
            #pragma unroll
            for (int kh = 0; kh < 3; ++kh)
                #pragma unroll
                for (int kw = 0; kw < 3; ++kw) {
                    const double wv = wr[(kh * 3 + kw) * 3 + ci];
                    acc[0][0] += xw[kh][kw]         * wv;
                    acc[0][1] += xw[kh][kw + 1]     * wv;
                    acc[1][0] += xw[kh + 1][kw]     * wv;
                    acc[1][1] += xw[kh + 1][kw + 1] * wv;
                }
        }
        int m = 0;
        #pragma unroll
        for (int r = 0; r < 2; ++r)
            #pragma unroll
            for (int c = 0; c < 2; ++c) {
                double y = acc[r][c] + bco;
                double lv = fmin(fmax(rint(y / sa), 0.0), 15.0);
                int li = (int)lv;
                if (li > m) m = li;
            }
        outrow[(t * 16 + g) * 16 + co] = (uint8_t)m;
    }
}

// ---------------------------------------------------------------------------
// Int conv layers 2..5: exact int32 dot4 + f64 epilogue
// ---------------------------------------------------------------------------
template<int CI, int CO, int H, int W, int NS>
__global__ __launch_bounds__(256) void convq_kernel(
    const uint8_t* __restrict__ ain, const int8_t* __restrict__ qk,
    const float* __restrict__ bias, const float* __restrict__ wscales, int widx,
    const float* __restrict__ act_scales, int sin_idx, int sout_idx,
    uint8_t* __restrict__ aout)
{
    constexpr int RCO = 8;
    constexpr int CG = CO / RCO;
    constexpr int OH = H / 2, OW = W / 2;
    constexpr int PH = H + 2, PW = W + 2;
    constexpr int XW = NS * PH * PW * (CI / 4);
    static_assert(NS * OH * OW * CG == 256, "one job per thread");
    __shared__ alignas(16) uint32_t xin[XW];

    const int tid = threadIdx.x;
    const int n0 = blockIdx.x * NS;
    for (int i = tid; i < XW; i += 256) xin[i] = 0u;
    __syncthreads();
    const uint32_t* src = reinterpret_cast<const uint32_t*>(ain + (size_t)n0 * H * W * CI);
    constexpr int NLOAD = NS * H * W * (CI / 4);
    for (int i = tid; i < NLOAD; i += 256) {
        int c4 = i % (CI / 4);
        int w_ = (i / (CI / 4)) % W;
        int h_ = (i / (CI / 4 * W)) % H;
        int s_ = i / (CI / 4 * W * H);
        xin[((s_ * PH + h_ + 1) * PW + (w_ + 1)) * (CI / 4) + c4] = src[i];
    }
    __syncthreads();

    const int cg = tid % CG;
    const int pw = (tid / CG) % OW;
    const int ph = (tid / (CG * OW)) % OH;
    const int s  = tid / (CG * OW * OH);
    const int co0 = cg * RCO;

    int accK[2][2][RCO] = {};
    const uint32_t* xbase = xin + s * PH * PW * (CI / 4);

    #pragma unroll
    for (int kh = 0; kh < 3; ++kh)
        #pragma unroll
        for (int kw = 0; kw < 3; ++kw) {
            for (int c16 = 0; c16 < CI / 16; ++c16) {
                uint4 xv[2][2];
                #pragma unroll
                for (int r = 0; r < 2; ++r)
                    #pragma unroll
                    for (int c = 0; c < 2; ++c) {
                        const int ih = 2 * ph + r + kh, iw = 2 * pw + c + kw;
                        xv[r][c] = *reinterpret_cast<const uint4*>(
                            xbase + (ih * PW + iw) * (CI / 4) + c16 * 4);
                    }
                #pragma unroll
                for (int j = 0; j < RCO; ++j) {
                    const size_t wo = ((size_t)(co0 + j) * 9 + kh * 3 + kw) * CI + c16 * 16;
                    uint4 wkv = *reinterpret_cast<const uint4*>(qk + wo);
                    #pragma unroll
                    for (int r = 0; r < 2; ++r)
                        #pragma unroll
                        for (int c = 0; c < 2; ++c)
                            accK[r][c][j] = dot16(xv[r][c], wkv, accK[r][c][j]);
                }
            }
        }

    const double sW  = (double)wscales[widx] / 7.0;
    const double saI = (double)act_scales[sin_idx];
    const double saO = (double)act_scales[sout_idx];
    uint32_t p0 = 0, p1 = 0;
    #pragma unroll
    for (int j = 0; j < RCO; ++j) {
        const double bj = (double)bias[co0 + j];
        int m = 0;
        #pragma unroll
        for (int r = 0; r < 2; ++r)
            #pragma unroll
            for (int c = 0; c < 2; ++c) {
                double y = ((double)accK[r][c][j] * sW) * saI + bj;
                double lv = fmin(fmax(rint(y / saO), 0.0), 15.0);
                int li = (int)lv;
                if (li > m) m = li;
            }
        if (j < 4) p0 |= (uint32_t)m << (8 * j);
        else       p1 |= (uint32_t)m << (8 * (j - 4));
    }
    uint8_t* dst = aout + (((size_t)(n0 + s) * OH * OW + ph * OW + pw) * CO + co0);
    uint2 pv; pv.x = p0; pv.y = p1;
    *reinterpret_cast<uint2*>(dst) = pv;
}

// ---------------------------------------------------------------------------
// FC1: (2048,256) u8 x (512,256) i8 -> f64 epilogue -> u8 levels (2048,512)
// block = 64 samples x 128 outputs, LDS-tiled
// ---------------------------------------------------------------------------
__global__ __launch_bounds__(256) void fc1_kernel(
    const uint8_t* __restrict__ a5, const int8_t* __restrict__ qk,
    const float* __restrict__ bias, const float* __restrict__ scales,
    const float* __restrict__ act, uint8_t* __restrict__ a6)
{
    __shared__ alignas(16) uint8_t at[64 * 256];
    __shared__ alignas(16) uint8_t wt[128 * 256];
    const int tid = threadIdx.x;
    const int n0 = (blockIdx.x >> 2) * 64;
    const int o0 = (blockIdx.x & 3) * 128;
    {
        const uint4* srca = reinterpret_cast<const uint4*>(a5 + (size_t)n0 * 256);
        uint4* dsta = reinterpret_cast<uint4*>(at);
        for (int i = tid; i < 64 * 256 / 16; i += 256) dsta[i] = srca[i];
        const uint4* srcw = reinterpret_cast<const uint4*>(qk + (size_t)o0 * 256);
        uint4* dstw = reinterpret_cast<uint4*>(wt);
        for (int i = tid; i < 128 * 256 / 16; i += 256) dstw[i] = srcw[i];
    }
    __syncthreads();
    const int ng = tid & 15, og = tid >> 4;
    const int nl = ng * 4, ol = og * 8;
    int acc[4][8] = {};
    const uint4* a4p = reinterpret_cast<const uint4*>(at);
    const uint4* w4p = reinterpret_cast<const uint4*>(wt);
    for (int c16 = 0; c16 < 16; ++c16) {
        uint4 av[4], wv[8];
        #pragma unroll
        for (int j = 0; j < 4; ++j) av[j] = a4p[(nl + j) * 16 + c16];
        #pragma unroll
        for (int k = 0; k < 8; ++k) wv[k] = w4p[(ol + k) * 16 + c16];
        #pragma unroll
        for (int j = 0; j < 4; ++j)
            #pragma unroll
            for (int k = 0; k < 8; ++k)
                acc[j][k] = dot16(av[j], wv[k], acc[j][k]);
    }
    const double sW = (double)scales[5] / 7.0;
    const double saI = (double)act[4], saO = (double)act[5];
    #pragma unroll
    for (int j = 0; j < 4; ++j) {
        uint32_t p0 = 0, p1 = 0;
        #pragma unroll
        for (int k = 0; k < 8; ++k) {
            double y = ((double)acc[j][k] * sW) * saI + (double)bias[o0 + ol + k];
            double lv = fmin(fmax(rint(y / saO), 0.0), 15.0);
            uint32_t li = (uint32_t)(int)lv;
            if (k < 4) p0 |= li << (8 * k); else p1 |= li << (8 * (k - 4));
        }
        uint2 pv; pv.x = p0; pv.y = p1;
        *reinterpret_cast<uint2*>(a6 + (size_t)(n0 + nl + j) * 512 + o0 + ol) = pv;
    }
}

// ---------------------------------------------------------------------------
// FC2 + quant_identity + softmax (all f64): one wave per sample
// ---------------------------------------------------------------------------
__global__ __launch_bounds__(256) void fc2_softmax_kernel(
    const uint8_t* __restrict__ a6, const int8_t* __restrict__ qk,
    const float* __restrict__ bias, const float* __restrict__ scales,
    const float* __restrict__ act, float* __restrict__ out)
{
    const int tid = threadIdx.x;
    const int wv = tid >> 6, lane = tid & 63;
    const int n = blockIdx.x * 4 + wv;
    const int o = lane;
    const uint32_t* arow = reinterpret_cast<const uint32_t*>(a6 + (size_t)n * 512);
    int acc = 0;
    if (o < 43) {
        const uint32_t* krow = reinterpret_cast<const uint32_t*>(qk + (size_t)o * 512);
        for (int c4 = 0; c4 < 128; ++c4) acc = dot4(arow[c4], krow[c4], acc);
    }
    const double sW = (double)scales[6] / 7.0;
    const double saI = (double)act[5], saO = (double)act[6];
    double z = -1.0e300;
    if (o < 43) {
        double y = ((double)acc * sW) * saI + (double)bias[o];
        double lv = fmin(fmax(rint(y / saO), -8.0), 7.0);
        z = lv * saO;
    }
    double m = z;
    #pragma unroll
    for (int off = 32; off; off >>= 1) m = fmax(m, __shfl_xor(m, off));
    double e = (o < 43) ? exp(z - m) : 0.0;
    double ssum = e;
    #pragma unroll
    for (int off = 32; off; off >>= 1) ssum += __shfl_xor(ssum, off);
    if (o < 43) out[(size_t)n * 43 + o] = (float)(e / ssum);
}

// ---------------------------------------------------------------------------
extern "C" void kernel_launch(void* const* d_in, const int* in_sizes, int n_in,
                              void* d_out, int out_size, void* d_ws, size_t ws_size,
                              hipStream_t stream) {
    const float* x   = (const float*)d_in[0];
    const float* w1  = (const float*)d_in[1];  const float* b1  = (const float*)d_in[2];
    const float* w2  = (const float*)d_in[3];  const float* b2  = (const float*)d_in[4];
    const float* w3  = (const float*)d_in[5];  const float* b3  = (const float*)d_in[6];
    const float* w4  = (const float*)d_in[7];  const float* b4  = (const float*)d_in[8];
    const float* w5  = (const float*)d_in[9];  const float* b5  = (const float*)d_in[10];
    const float* wf1 = (const float*)d_in[11]; const float* bf1 = (const float*)d_in[12];
    const float* wf2 = (const float*)d_in[13]; const float* bf2 = (const float*)d_in[14];
    const float* act = (const float*)d_in[15];
    float* out = (float*)d_out;

    uint8_t* wsb = (uint8_t*)d_ws;
    size_t off = 0;
    auto alloc = [&](size_t bytes) -> uint8_t* {
        uint8_t* r = wsb + off;
        off += (bytes + 255) & ~(size_t)255;
        return r;
    };
    float*   scales  = (float*)alloc(32 * 4);
    float*   partial = (float*)alloc(224 * 4);
    int8_t*  qk1  = (int8_t*)alloc(432);
    int8_t*  qk2  = (int8_t*)alloc(4608);
    int8_t*  qk3  = (int8_t*)alloc(18432);
    int8_t*  qk4  = (int8_t*)alloc(73728);
    int8_t*  qk5  = (int8_t*)alloc(294912);
    int8_t*  qkf1 = (int8_t*)alloc(131072);
    int8_t*  qkf2 = (int8_t*)alloc(22016);
    uint8_t* a1 = alloc((size_t)2048 * 16 * 16 * 16);
    uint8_t* a2 = alloc((size_t)2048 * 8 * 8 * 32);
    uint8_t* a3 = alloc((size_t)2048 * 4 * 4 * 64);
    uint8_t* a4 = alloc((size_t)2048 * 2 * 2 * 128);
    uint8_t* a5 = alloc((size_t)2048 * 256);
    uint8_t* a6 = alloc((size_t)2048 * 512);

    // --- weight quantization (on-device, every call) ---
    absmax_part_kernel<<<224, 256, 0, stream>>>(w1, w2, w3, w4, w5, wf1, wf2, partial);
    absmax_final_kernel<<<7, 64, 0, stream>>>(partial, scales);
    qconvw_kernel<16, 3><<<2, 256, 0, stream>>>(w1, qk1, scales, 0);
    qconvw_kernel<32, 16><<<18, 256, 0, stream>>>(w2, qk2, scales, 1);
    qconvw_kernel<64, 32><<<72, 256, 0, stream>>>(w3, qk3, scales, 2);
    qconvw_kernel<128, 64><<<288, 256, 0, stream>>>(w4, qk4, scales, 3);
    qconvw_kernel<256, 128><<<1152, 256, 0, stream>>>(w5, qk5, scales, 4);
    qfcw_kernel<<<512, 256, 0, stream>>>(wf1, qkf1, scales, 5, 131072);
    qfcw_kernel<<<86, 256, 0, stream>>>(wf2, qkf2, scales, 6, 22016);

    // --- network ---
    conv1_kernel<<<2048, 256, 0, stream>>>(x, qk1, b1, scales, act, a1);
    convq_kernel<16, 32, 16, 16, 1><<<2048, 256, 0, stream>>>(a1, qk2, b2, scales, 1, act, 0, 1, a2);
    convq_kernel<32, 64, 8, 8, 2><<<1024, 256, 0, stream>>>(a2, qk3, b3, scales, 2, act, 1, 2, a3);
    convq_kernel<64, 128, 4, 4, 4><<<512, 256, 0, stream>>>(a3, qk4, b4, scales, 3, act, 2, 3, a4);
    convq_kernel<128, 256, 2, 2, 8><<<256, 256, 0, stream>>>(a4, qk5, b5, scales, 4, act, 3, 4, a5);
    fc1_kernel<<<128, 256, 0, stream>>>(a5, qkf1, bf1, scales, act, a6);
    fc2_softmax_kernel<<<512, 256, 0, stream>>>(a6, qkf2, bf2, scales, act, out);

    (void)in_sizes; (void)n_in; (void)out_size; (void)ws_size;
}

// Round 9
// 509.779 us; speedup vs baseline: 1.0079x; 1.0079x over previous
//
#include <hip/hip_runtime.h>
#include <hip/hip_bf16.h>
#include <cstdint>
#include <cmath>

// ---------------------------------------------------------------------------
// Quantized TSRNet forward — bit-faithful emulation of the np FLOAT64
// reference. Numerics contract (verified round 8: absmax 1.96e-5):
//   - s64 = (f64)absmax(w) / 7.0 ; k = clip(rint_f64(w/s64), -7, 7)
//   - conv2..5/fc: exact int32 dot4 accumulation; f64 epilogue.
//   - conv1: f64 accumulation of (f64)x * fl64(k*s64).
// Round-9 perf changes (counter-driven, int-exact => no numeric risk):
//   - convq: weight loads hoisted into wv[RCO] before the dot16 block
//     (round-8 profile: conv2 87.9us, VALUBusy 29% -- serialized
//      load->use chains per j were exposing ~8x load latency per (kh,kw))
//   - convq: weights staged in LDS for conv2 (4.6KB) / conv3 (18KB)
//   - weight-quant preamble fused 7 dispatches -> 1
// ---------------------------------------------------------------------------

#if defined(__has_builtin)
#if __has_builtin(__builtin_amdgcn_sdot4)
#define HAVE_SDOT4 1
#endif
#endif

__device__ __forceinline__ int dot4(unsigned int a, unsigned int b, int c) {
#ifdef HAVE_SDOT4
    return __builtin_amdgcn_sdot4((int)a, (int)b, c, false);
#else
    #pragma unroll
    for (int k = 0; k < 4; ++k) {
        int av = (int)(signed char)((a >> (8 * k)) & 0xffu);
        int bv = (int)(signed char)((b >> (8 * k)) & 0xffu);
        c += av * bv;
    }
    return c;
#endif
}

__device__ __forceinline__ int dot16(uint4 a, uint4 b, int c) {
    c = dot4(a.x, b.x, c);
    c = dot4(a.y, b.y, c);
    c = dot4(a.z, b.z, c);
    c = dot4(a.w, b.w, c);
    return c;
}

// ---------------------------------------------------------------------------
// absmax per weight tensor; scales[t] = absmax (fp32, exact)
// ---------------------------------------------------------------------------
__global__ __launch_bounds__(256) void absmax_part_kernel(
    const float* __restrict__ w1, const float* __restrict__ w2,
    const float* __restrict__ w3, const float* __restrict__ w4,
    const float* __restrict__ w5, const float* __restrict__ wf1,
    const float* __restrict__ wf2, float* __restrict__ partial)
{
    const int t = blockIdx.x >> 5;
    const int k = blockIdx.x & 31;
    const float* p; int n;
    switch (t) {
        case 0: p = w1;  n = 432;    break;
        case 1: p = w2;  n = 4608;   break;
        case 2: p = w3;  n = 18432;  break;
        case 3: p = w4;  n = 73728;  break;
        case 4: p = w5;  n = 294912; break;
        case 5: p = wf1; n = 131072; break;
        default: p = wf2; n = 22016; break;
    }
    float m = 0.f;
    for (int i = k * 256 + threadIdx.x; i < n; i += 32 * 256)
        m = fmaxf(m, fabsf(p[i]));
    #pragma unroll
    for (int off = 32; off; off >>= 1) m = fmaxf(m, __shfl_xor(m, off));
    __shared__ float red[4];
    if ((threadIdx.x & 63) == 0) red[threadIdx.x >> 6] = m;
    __syncthreads();
    if (threadIdx.x == 0) {
        m = fmaxf(fmaxf(red[0], red[1]), fmaxf(red[2], red[3]));
        partial[blockIdx.x] = m;
    }
}

__global__ __launch_bounds__(64) void absmax_final_kernel(
    const float* __restrict__ partial, float* __restrict__ scales)
{
    const int t = blockIdx.x;
    float m = (threadIdx.x < 32) ? partial[t * 32 + threadIdx.x] : 0.f;
    #pragma unroll
    for (int off = 32; off; off >>= 1) m = fmaxf(m, __shfl_xor(m, off));
    if (threadIdx.x == 0) scales[t] = m;   // absmax; consumers divide by 7 in f64
}

// ---------------------------------------------------------------------------
// Fused weight quantization: all 7 tensors in one dispatch.
// conv tensors: OIHW -> OHWI permute; fc tensors: linear.
// f64 round-half-even, np-exact (same math as round-8 verified kernels).
// ---------------------------------------------------------------------------
__global__ __launch_bounds__(256) void quantw_all_kernel(
    const float* __restrict__ w1, const float* __restrict__ w2,
    const float* __restrict__ w3, const float* __restrict__ w4,
    const float* __restrict__ w5, const float* __restrict__ wf1,
    const float* __restrict__ wf2,
    int8_t* __restrict__ q1, int8_t* __restrict__ q2,
    int8_t* __restrict__ q3, int8_t* __restrict__ q4,
    int8_t* __restrict__ q5, int8_t* __restrict__ qf1,
    int8_t* __restrict__ qf2,
    const float* __restrict__ scales)
{
    const int i = blockIdx.x * 256 + threadIdx.x;
    if (i >= 545200) return;
    int t, base, ci;
    const float* w; int8_t* q;
    if      (i < 432)    { t = 0; base = 0;      w = w1;  q = q1;  ci = 3;   }
    else if (i < 5040)   { t = 1; base = 432;    w = w2;  q = q2;  ci = 16;  }
    else if (i < 23472)  { t = 2; base = 5040;   w = w3;  q = q3;  ci = 32;  }
    else if (i < 97200)  { t = 3; base = 23472;  w = w4;  q = q4;  ci = 64;  }
    else if (i < 392112) { t = 4; base = 97200;  w = w5;  q = q5;  ci = 128; }
    else if (i < 523184) { t = 5; base = 392112; w = wf1; q = qf1; ci = 0;   }
    else                 { t = 6; base = 523184; w = wf2; q = qf2; ci = 0;   }
    const int li = i - base;
    const double s = (double)scales[t] / 7.0;
    const double kf = (s > 0.0) ? fmin(fmax(rint((double)w[li] / s), -7.0), 7.0) : 0.0;
    if (ci) {
        int kw = li % 3, kh = (li / 3) % 3, c = (li / 9) % ci, co = li / (9 * ci);
        q[((co * 3 + kh) * 3 + kw) * ci + c] = (int8_t)kf;
    } else {
        q[li] = (int8_t)kf;
    }
}

// ---------------------------------------------------------------------------
// Conv1: fp32 (2048,3,32,32) -> f64 acc with fl64(k*s64) weights -> quant_relu
// -> pool -> u8 levels NHWC (2048,16,16,16)
// ---------------------------------------------------------------------------
__global__ __launch_bounds__(256) void conv1_kernel(
    const float* __restrict__ x, const int8_t* __restrict__ qk,
    const float* __restrict__ bias, const float* __restrict__ wscales,
    const float* __restrict__ act_scales, uint8_t* __restrict__ a1)
{
    __shared__ alignas(16) float xin[3 * 34 * 34];
    const int tid = threadIdx.x;
    const int n = blockIdx.x;
    for (int i = tid; i < 3 * 34 * 34; i += 256) xin[i] = 0.f;
    __syncthreads();
    const float* xs = x + (size_t)n * 3072;
    for (int i = tid; i < 3072; i += 256) {
        int c = i >> 10, pix = i & 1023, h = pix >> 5, w = pix & 31;
        xin[c * 1156 + (h + 1) * 34 + (w + 1)] = xs[i];
    }
    __syncthreads();

    const double s64 = (double)wscales[0] / 7.0;
    const double sa = (double)act_scales[0];
    const int co = tid & 15, g = tid >> 4;
    double wr[27];
    #pragma unroll
    for (int k = 0; k < 27; ++k)
        wr[k] = (double)qk[co * 27 + k] * s64;          // fl64(k*s64) = np weight
    const double bco = (double)bias[co];
    uint8_t* outrow = a1 + (size_t)n * 4096;

    for (int t = 0; t < 16; ++t) {
        double acc[2][2] = {{0.0, 0.0}, {0.0, 0.0}};
        #pragma unroll
        for (int ci = 0; ci < 3; ++ci) {
            double xw[4][4];
            #pragma unroll
            for (int rr = 0; rr < 4; ++rr) {
                const int base = ci * 1156 + (2 * t + rr) * 34 + 2 * g;
                float2 v0 = *reinterpret_cast<const float2*>(&xin[base]);
                float2 v1 = *reinterpret_cast<const float2*>(&xin[base + 2]);
                xw[rr][0] = (double)v0.x; xw[rr][1] = (double)v0.y;
                xw[rr][2] = (double)v1.x; xw[rr][3] = (double)v1.y;
            }
            #pragma unroll
            for (int kh = 0; kh < 3; ++kh)
                #pragma unroll
                for (int kw = 0; kw < 3; ++kw) {
                    const double wv = wr[(kh * 3 + kw) * 3 + ci];
                    acc[0][0] += xw[kh][kw]         * wv;
                    acc[0][1] += xw[kh][kw + 1]     * wv;
                    acc[1][0] += xw[kh + 1][kw]     * wv;
                    acc[1][1] += xw[kh + 1][kw + 1] * wv;
                }
        }
        int m = 0;
        #pragma unroll
        for (int r = 0; r < 2; ++r)
            #pragma unroll
            for (int c = 0; c < 2; ++c) {
                double y = acc[r][c] + bco;
                double lv = fmin(fmax(rint(y / sa), 0.0), 15.0);
                int li = (int)lv;
                if (li > m) m = li;
            }
        outrow[(t * 16 + g) * 16 + co] = (uint8_t)m;
    }
}

// ---------------------------------------------------------------------------
// Int conv layers 2..5: exact int32 dot4 + f64 epilogue.
// WLDS: stage the whole weight tile in LDS (layers 2,3).
// All loads of a (kh,kw,c16) iteration are hoisted before the dot16 block.
// ---------------------------------------------------------------------------
template<int CI, int CO, int H, int W, int NS, bool WLDS>
__global__ __launch_bounds__(256) void convq_kernel(
    const uint8_t* __restrict__ ain, const int8_t* __restrict__ qk,
    const float* __restrict__ bias, const float* __restrict__ wscales, int widx,
    const float* __restrict__ act_scales, int sin_idx, int sout_idx,
    uint8_t* __restrict__ aout)
{
    constexpr int RCO = 8;
    constexpr int CG = CO / RCO;
    constexpr int OH = H / 2, OW = W / 2;
    constexpr int PH = H + 2, PW = W + 2;
    constexpr int XW = NS * PH * PW * (CI / 4);
    constexpr int NW4 = CO * 9 * CI / 16;            // weight tile in uint4
    static_assert(NS * OH * OW * CG == 256, "one job per thread");
    __shared__ alignas(16) uint32_t xin[XW];
    __shared__ alignas(16) uint4 wlds[WLDS ? NW4 : 1];

    const int tid = threadIdx.x;
    const int n0 = blockIdx.x * NS;
    for (int i = tid; i < XW; i += 256) xin[i] = 0u;
    __syncthreads();
    const uint32_t* src = reinterpret_cast<const uint32_t*>(ain + (size_t)n0 * H * W * CI);
    constexpr int NLOAD = NS * H * W * (CI / 4);
    for (int i = tid; i < NLOAD; i += 256) {
        int c4 = i % (CI / 4);
        int w_ = (i / (CI / 4)) % W;
        int h_ = (i / (CI / 4 * W)) % H;
        int s_ = i / (CI / 4 * W * H);
        xin[((s_ * PH + h_ + 1) * PW + (w_ + 1)) * (CI / 4) + c4] = src[i];
    }
    if (WLDS) {
        const uint4* wsrc = reinterpret_cast<const uint4*>(qk);
        for (int i = tid; i < NW4; i += 256) wlds[i] = wsrc[i];
    }
    __syncthreads();

    const int cg = tid % CG;
    const int pw = (tid / CG) % OW;
    const int ph = (tid / (CG * OW)) % OH;
    const int s  = tid / (CG * OW * OH);
    const int co0 = cg * RCO;

    int accK[2][2][RCO] = {};
    const uint32_t* xbase = xin + s * PH * PW * (CI / 4);
    const uint4* wglob = reinterpret_cast<const uint4*>(qk);

    #pragma unroll
    for (int kh = 0; kh < 3; ++kh)
        #pragma unroll
        for (int kw = 0; kw < 3; ++kw) {
            for (int c16 = 0; c16 < CI / 16; ++c16) {
                // ---- hoisted loads: 4 x-tiles + RCO weight rows ----
                uint4 xv[2][2];
                #pragma unroll
                for (int r = 0; r < 2; ++r)
                    #pragma unroll
                    for (int c = 0; c < 2; ++c) {
                        const int ih = 2 * ph + r + kh, iw = 2 * pw + c + kw;
                        xv[r][c] = *reinterpret_cast<const uint4*>(
                            xbase + (ih * PW + iw) * (CI / 4) + c16 * 4);
                    }
                uint4 wv[RCO];
                const int wo4 = (co0 * 9 + kh * 3 + kw) * (CI / 16) + c16;
                #pragma unroll
                for (int j = 0; j < RCO; ++j)
                    wv[j] = WLDS ? wlds[wo4 + j * 9 * (CI / 16)]
                                 : wglob[wo4 + j * 9 * (CI / 16)];
                // ---- compute: 32 independent dot16 chains ----
                #pragma unroll
                for (int j = 0; j < RCO; ++j)
                    #pragma unroll
                    for (int r = 0; r < 2; ++r)
                        #pragma unroll
                        for (int c = 0; c < 2; ++c)
                            accK[r][c][j] = dot16(xv[r][c], wv[j], accK[r][c][j]);
            }
        }

    const double sW  = (double)wscales[widx] / 7.0;
    const double saI = (double)act_scales[sin_idx];
    const double saO = (double)act_scales[sout_idx];
    uint32_t p0 = 0, p1 = 0;
    #pragma unroll
    for (int j = 0; j < RCO; ++j) {
        const double bj = (double)bias[co0 + j];
        int m = 0;
        #pragma unroll
        for (int r = 0; r < 2; ++r)
            #pragma unroll
            for (int c = 0; c < 2; ++c) {
                double y = ((double)accK[r][c][j] * sW) * saI + bj;
                double lv = fmin(fmax(rint(y / saO), 0.0), 15.0);
                int li = (int)lv;
                if (li > m) m = li;
            }
        if (j < 4) p0 |= (uint32_t)m << (8 * j);
        else       p1 |= (uint32_t)m << (8 * (j - 4));
    }
    uint8_t* dst = aout + (((size_t)(n0 + s) * OH * OW + ph * OW + pw) * CO + co0);
    uint2 pv; pv.x = p0; pv.y = p1;
    *reinterpret_cast<uint2*>(dst) = pv;
}

// ---------------------------------------------------------------------------
// FC1: (2048,256) u8 x (512,256) i8 -> f64 epilogue -> u8 levels (2048,512)
// block = 64 samples x 128 outputs, LDS-tiled
// ---------------------------------------------------------------------------
__global__ __launch_bounds__(256) void fc1_kernel(
    const uint8_t* __restrict__ a5, const int8_t* __restrict__ qk,
    const float* __restrict__ bias, const float* __restrict__ scales,
    const float* __restrict__ act, uint8_t* __restrict__ a6)
{
    __shared__ alignas(16) uint8_t at[64 * 256];
    __shared__ alignas(16) uint8_t wt[128 * 256];
    const int tid = threadIdx.x;
    const int n0 = (blockIdx.x >> 2) * 64;
    const int o0 = (blockIdx.x & 3) * 128;
    {
        const uint4* srca = reinterpret_cast<const uint4*>(a5 + (size_t)n0 * 256);
        uint4* dsta = reinterpret_cast<uint4*>(at);
        for (int i = tid; i < 64 * 256 / 16; i += 256) dsta[i] = srca[i];
        const uint4* srcw = reinterpret_cast<const uint4*>(qk + (size_t)o0 * 256);
        uint4* dstw = reinterpret_cast<uint4*>(wt);
        for (int i = tid; i < 128 * 256 / 16; i += 256) dstw[i] = srcw[i];
    }
    __syncthreads();
    const int ng = tid & 15, og = tid >> 4;
    const int nl = ng * 4, ol = og * 8;
    int acc[4][8] = {};
    const uint4* a4p = reinterpret_cast<const uint4*>(at);
    const uint4* w4p = reinterpret_cast<const uint4*>(wt);
    for (int c16 = 0; c16 < 16; ++c16) {
        uint4 av[4], wv[8];
        #pragma unroll
        for (int j = 0; j < 4; ++j) av[j] = a4p[(nl + j) * 16 + c16];
        #pragma unroll
        for (int k = 0; k < 8; ++k) wv[k] = w4p[(ol + k) * 16 + c16];
        #pragma unroll
        for (int j = 0; j < 4; ++j)
            #pragma unroll
            for (int k = 0; k < 8; ++k)
                acc[j][k] = dot16(av[j], wv[k], acc[j][k]);
    }
    const double sW = (double)scales[5] / 7.0;
    const double saI = (double)act[4], saO = (double)act[5];
    #pragma unroll
    for (int j = 0; j < 4; ++j) {
        uint32_t p0 = 0, p1 = 0;
        #pragma unroll
        for (int k = 0; k < 8; ++k) {
            double y = ((double)acc[j][k] * sW) * saI + (double)bias[o0 + ol + k];
            double lv = fmin(fmax(rint(y / saO), 0.0), 15.0);
            uint32_t li = (uint32_t)(int)lv;
            if (k < 4) p0 |= li << (8 * k); else p1 |= li << (8 * (k - 4));
        }
        uint2 pv; pv.x = p0; pv.y = p1;
        *reinterpret_cast<uint2*>(a6 + (size_t)(n0 + nl + j) * 512 + o0 + ol) = pv;
    }
}

// ---------------------------------------------------------------------------
// FC2 + quant_identity + softmax (all f64): one wave per sample
// ---------------------------------------------------------------------------
__global__ __launch_bounds__(256) void fc2_softmax_kernel(
    const uint8_t* __restrict__ a6, const int8_t* __restrict__ qk,
    const float* __restrict__ bias, const float* __restrict__ scales,
    const float* __restrict__ act, float* __restrict__ out)
{
    const int tid = threadIdx.x;
    const int wv = tid >> 6, lane = tid & 63;
    const int n = blockIdx.x * 4 + wv;
    const int o = lane;
    const uint32_t* arow = reinterpret_cast<const uint32_t*>(a6 + (size_t)n * 512);
    int acc = 0;
    if (o < 43) {
        const uint32_t* krow = reinterpret_cast<const uint32_t*>(qk + (size_t)o * 512);
        for (int c4 = 0; c4 < 128; ++c4) acc = dot4(arow[c4], krow[c4], acc);
    }
    const double sW = (double)scales[6] / 7.0;
    const double saI = (double)act[5], saO = (double)act[6];
    double z = -1.0e300;
    if (o < 43) {
        double y = ((double)acc * sW) * saI + (double)bias[o];
        double lv = fmin(fmax(rint(y / saO), -8.0), 7.0);
        z = lv * saO;
    }
    double m = z;
    #pragma unroll
    for (int off = 32; off; off >>= 1) m = fmax(m, __shfl_xor(m, off));
    double e = (o < 43) ? exp(z - m) : 0.0;
    double ssum = e;
    #pragma unroll
    for (int off = 32; off; off >>= 1) ssum += __shfl_xor(ssum, off);
    if (o < 43) out[(size_t)n * 43 + o] = (float)(e / ssum);
}

// ---------------------------------------------------------------------------
extern "C" void kernel_launch(void* const* d_in, const int* in_sizes, int n_in,
                              void* d_out, int out_size, void* d_ws, size_t ws_size,
                              hipStream_t stream) {
    const float* x   = (const float*)d_in[0];
    const float* w1  = (const float*)d_in[1];  const float* b1  = (const float*)d_in[2];
    const float* w2  = (const float*)d_in[3];  const float* b2  = (const float*)d_in[4];
    const float* w3  = (const float*)d_in[5];  const float* b3  = (const float*)d_in[6];
    const float* w4  = (const float*)d_in[7];  const float* b4  = (const float*)d_in[8];
    const float* w5  = (const float*)d_in[9];  const float* b5  = (const float*)d_in[10];
    const float* wf1 = (const float*)d_in[11]; const float* bf1 = (const float*)d_in[12];
    const float* wf2 = (const float*)d_in[13]; const float* bf2 = (const float*)d_in[14];
    const float* act = (const float*)d_in[15];
    float* out = (float*)d_out;

    uint8_t* wsb = (uint8_t*)d_ws;
    size_t off = 0;
    auto alloc = [&](size_t bytes) -> uint8_t* {
        uint8_t* r = wsb + off;
        off += (bytes + 255) & ~(size_t)255;
        return r;
    };
    float*   scales  = (float*)alloc(32 * 4);
    float*   partial = (float*)alloc(224 * 4);
    int8_t*  qk1  = (int8_t*)alloc(432);
    int8_t*  qk2  = (int8_t*)alloc(4608);
    int8_t*  qk3  = (int8_t*)alloc(18432);
    int8_t*  qk4  = (int8_t*)alloc(73728);
    int8_t*  qk5  = (int8_t*)alloc(294912);
    int8_t*  qkf1 = (int8_t*)alloc(131072);
    int8_t*  qkf2 = (int8_t*)alloc(22016);
    uint8_t* a1 = alloc((size_t)2048 * 16 * 16 * 16);
    uint8_t* a2 = alloc((size_t)2048 * 8 * 8 * 32);
    uint8_t* a3 = alloc((size_t)2048 * 4 * 4 * 64);
    uint8_t* a4 = alloc((size_t)2048 * 2 * 2 * 128);
    uint8_t* a5 = alloc((size_t)2048 * 256);
    uint8_t* a6 = alloc((size_t)2048 * 512);

    // --- weight quantization (3 dispatches) ---
    absmax_part_kernel<<<224, 256, 0, stream>>>(w1, w2, w3, w4, w5, wf1, wf2, partial);
    absmax_final_kernel<<<7, 64, 0, stream>>>(partial, scales);
    quantw_all_kernel<<<2130, 256, 0, stream>>>(
        w1, w2, w3, w4, w5, wf1, wf2,
        qk1, qk2, qk3, qk4, qk5, qkf1, qkf2, scales);

    // --- network ---
    conv1_kernel<<<2048, 256, 0, stream>>>(x, qk1, b1, scales, act, a1);
    convq_kernel<16, 32, 16, 16, 1, true><<<2048, 256, 0, stream>>>(a1, qk2, b2, scales, 1, act, 0, 1, a2);
    convq_kernel<32, 64, 8, 8, 2, true><<<1024, 256, 0, stream>>>(a2, qk3, b3, scales, 2, act, 1, 2, a3);
    convq_kernel<64, 128, 4, 4, 4, false><<<512, 256, 0, stream>>>(a3, qk4, b4, scales, 3, act, 2, 3, a4);
    convq_kernel<128, 256, 2, 2, 8, false><<<256, 256, 0, stream>>>(a4, qk5, b5, scales, 4, act, 3, 4, a5);
    fc1_kernel<<<128, 256, 0, stream>>>(a5, qkf1, bf1, scales, act, a6);
    fc2_softmax_kernel<<<512, 256, 0, stream>>>(a6, qkf2, bf2, scales, act, out);

    (void)in_sizes; (void)n_in; (void)out_size; (void)ws_size;
}

// Round 13
// 496.870 us; speedup vs baseline: 1.0341x; 1.0260x over previous
//
#include <hip/hip_runtime.h>
#include <hip/hip_bf16.h>
#include <cstdint>
#include <cmath>

// ---------------------------------------------------------------------------
// Quantized TSRNet forward — bit-faithful emulation of the np FLOAT64
// reference. Numerics contract (verified round 8/9: absmax 1.96e-5):
//   - s64 = (f64)absmax(w) / 7.0 ; k = clip(rint_f64(w/s64), -7, 7)
//   - conv2..5/fc: exact int32 dot4 accumulation; f64 epilogue.
//   - conv1: f64 accumulation of (f64)x * fl64(k*s64).
// Round-10: REVERT LDS weight staging (round-9 regression: wlds layout put
// all 8 co-groups in one bank -> 1.73e7 bank-conflict cycles ~= +28us on
// conv3). Weights load from global (L1/L2-resident, tiny tensors), with the
// hoisted wv[RCO] block kept (evidence: conv2 left the top-5 in round 9).
// ---------------------------------------------------------------------------

#if defined(__has_builtin)
#if __has_builtin(__builtin_amdgcn_sdot4)
#define HAVE_SDOT4 1
#endif
#endif

__device__ __forceinline__ int dot4(unsigned int a, unsigned int b, int c) {
#ifdef HAVE_SDOT4
    return __builtin_amdgcn_sdot4((int)a, (int)b, c, false);
#else
    #pragma unroll
    for (int k = 0; k < 4; ++k) {
        int av = (int)(signed char)((a >> (8 * k)) & 0xffu);
        int bv = (int)(signed char)((b >> (8 * k)) & 0xffu);
        c += av * bv;
    }
    return c;
#endif
}

__device__ __forceinline__ int dot16(uint4 a, uint4 b, int c) {
    c = dot4(a.x, b.x, c);
    c = dot4(a.y, b.y, c);
    c = dot4(a.z, b.z, c);
    c = dot4(a.w, b.w, c);
    return c;
}

// ---------------------------------------------------------------------------
// absmax per weight tensor; scales[t] = absmax (fp32, exact)
// ---------------------------------------------------------------------------
__global__ __launch_bounds__(256) void absmax_part_kernel(
    const float* __restrict__ w1, const float* __restrict__ w2,
    const float* __restrict__ w3, const float* __restrict__ w4,
    const float* __restrict__ w5, const float* __restrict__ wf1,
    const float* __restrict__ wf2, float* __restrict__ partial)
{
    const int t = blockIdx.x >> 5;
    const int k = blockIdx.x & 31;
    const float* p; int n;
    switch (t) {
        case 0: p = w1;  n = 432;    break;
        case 1: p = w2;  n = 4608;   break;
        case 2: p = w3;  n = 18432;  break;
        case 3: p = w4;  n = 73728;  break;
        case 4: p = w5;  n = 294912; break;
        case 5: p = wf1; n = 131072; break;
        default: p = wf2; n = 22016; break;
    }
    float m = 0.f;
    for (int i = k * 256 + threadIdx.x; i < n; i += 32 * 256)
        m = fmaxf(m, fabsf(p[i]));
    #pragma unroll
    for (int off = 32; off; off >>= 1) m = fmaxf(m, __shfl_xor(m, off));
    __shared__ float red[4];
    if ((threadIdx.x & 63) == 0) red[threadIdx.x >> 6] = m;
    __syncthreads();
    if (threadIdx.x == 0) {
        m = fmaxf(fmaxf(red[0], red[1]), fmaxf(red[2], red[3]));
        partial[blockIdx.x] = m;
    }
}

__global__ __launch_bounds__(64) void absmax_final_kernel(
    const float* __restrict__ partial, float* __restrict__ scales)
{
    const int t = blockIdx.x;
    float m = (threadIdx.x < 32) ? partial[t * 32 + threadIdx.x] : 0.f;
    #pragma unroll
    for (int off = 32; off; off >>= 1) m = fmaxf(m, __shfl_xor(m, off));
    if (threadIdx.x == 0) scales[t] = m;   // absmax; consumers divide by 7 in f64
}

// ---------------------------------------------------------------------------
// Fused weight quantization: all 7 tensors in one dispatch.
// conv tensors: OIHW -> OHWI permute; fc tensors: linear.
// f64 round-half-even, np-exact.
// ---------------------------------------------------------------------------
__global__ __launch_bounds__(256) void quantw_all_kernel(
    const float* __restrict__ w1, const float* __restrict__ w2,
    const float* __restrict__ w3, const float* __restrict__ w4,
    const float* __restrict__ w5, const float* __restrict__ wf1,
    const float* __restrict__ wf2,
    int8_t* __restrict__ q1, int8_t* __restrict__ q2,
    int8_t* __restrict__ q3, int8_t* __restrict__ q4,
    int8_t* __restrict__ q5, int8_t* __restrict__ qf1,
    int8_t* __restrict__ qf2,
    const float* __restrict__ scales)
{
    const int i = blockIdx.x * 256 + threadIdx.x;
    if (i >= 545200) return;
    int t, base, ci;
    const float* w; int8_t* q;
    if      (i < 432)    { t = 0; base = 0;      w = w1;  q = q1;  ci = 3;   }
    else if (i < 5040)   { t = 1; base = 432;    w = w2;  q = q2;  ci = 16;  }
    else if (i < 23472)  { t = 2; base = 5040;   w = w3;  q = q3;  ci = 32;  }
    else if (i < 97200)  { t = 3; base = 23472;  w = w4;  q = q4;  ci = 64;  }
    else if (i < 392112) { t = 4; base = 97200;  w = w5;  q = q5;  ci = 128; }
    else if (i < 523184) { t = 5; base = 392112; w = wf1; q = qf1; ci = 0;   }
    else                 { t = 6; base = 523184; w = wf2; q = qf2; ci = 0;   }
    const int li = i - base;
    const double s = (double)scales[t] / 7.0;
    const double kf = (s > 0.0) ? fmin(fmax(rint((double)w[li] / s), -7.0), 7.0) : 0.0;
    if (ci) {
        int kw = li % 3, kh = (li / 3) % 3, c = (li / 9) % ci, co = li / (9 * ci);
        q[((co * 3 + kh) * 3 + kw) * ci + c] = (int8_t)kf;
    } else {
        q[li] = (int8_t)kf;
    }
}

// ---------------------------------------------------------------------------
// Conv1: fp32 (2048,3,32,32) -> f64 acc with fl64(k*s64) weights -> quant_relu
// -> pool -> u8 levels NHWC (2048,16,16,16)
// ---------------------------------------------------------------------------
__global__ __launch_bounds__(256) void conv1_kernel(
    const float* __restrict__ x, const int8_t* __restrict__ qk,
    const float* __restrict__ bias, const float* __restrict__ wscales,
    const float* __restrict__ act_scales, uint8_t* __restrict__ a1)
{
    __shared__ alignas(16) float xin[3 * 34 * 34];
    const int tid = threadIdx.x;
    const int n = blockIdx.x;
    for (int i = tid; i < 3 * 34 * 34; i += 256) xin[i] = 0.f;
    __syncthreads();
    const float* xs = x + (size_t)n * 3072;
    for (int i = tid; i < 3072; i += 256) {
        int c = i >> 10, pix = i & 1023, h = pix >> 5, w = pix & 31;
        xin[c * 1156 + (h + 1) * 34 + (w + 1)] = xs[i];
    }
    __syncthreads();

    const double s64 = (double)wscales[0] / 7.0;
    const double sa = (double)act_scales[0];
    const int co = tid & 15, g = tid >> 4;
    double wr[27];
    #pragma unroll
    for (int k = 0; k < 27; ++k)
        wr[k] = (double)qk[co * 27 + k] * s64;          // fl64(k*s64) = np weight
    const double bco = (double)bias[co];
    uint8_t* outrow = a1 + (size_t)n * 4096;

    for (int t = 0; t < 16; ++t) {
        double acc[2][2] = {{0.0, 0.0}, {0.0, 0.0}};
        #pragma unroll
        for (int ci = 0; ci < 3; ++ci) {
            double xw[4][4];
            #pragma unroll
            for (int rr = 0; rr < 4; ++rr) {
                const int base = ci * 1156 + (2 * t + rr) * 34 + 2 * g;
                float2 v0 = *reinterpret_cast<const float2*>(&xin[base]);
                float2 v1 = *reinterpret_cast<const float2*>(&xin[base + 2]);
                xw[rr][0] = (double)v0.x; xw[rr][1] = (double)v0.y;
                xw[rr][2] = (double)v1.x; xw[rr][3] = (double)v1.y;
            }
            #pragma unroll
            for (int kh = 0; kh < 3; ++kh)
                #pragma unroll
                for (int kw = 0; kw < 3; ++kw) {
                    const double wv = wr[(kh * 3 + kw) * 3 + ci];
                    acc[0][0] += xw[kh][kw]         * wv;
                    acc[0][1] += xw[kh][kw + 1]     * wv;
                    acc[1][0] += xw[kh + 1][kw]     * wv;
                    acc[1][1] += xw[kh + 1][kw + 1] * wv;
                }
        }
        int m = 0;
        #pragma unroll
        for (int r = 0; r < 2; ++r)
            #pragma unroll
            for (int c = 0; c < 2; ++c) {
                double y = acc[r][c] + bco;
                double lv = fmin(fmax(rint(y / sa), 0.0), 15.0);
                int li = (int)lv;
                if (li > m) m = li;
            }
        outrow[(t * 16 + g) * 16 + co] = (uint8_t)m;
    }
}

// ---------------------------------------------------------------------------
// Int conv layers 2..5: exact int32 dot4 + f64 epilogue.
// Weights from GLOBAL (L1/L2-resident; round-9 LDS staging regressed via
// 8-way bank conflicts). All loads of a (kh,kw,c16) iteration hoisted
// before the dot16 block (independent -> latency overlapped).
// ---------------------------------------------------------------------------
template<int CI, int CO, int H, int W, int NS>
__global__ __launch_bounds__(256) void convq_kernel(
    const uint8_t* __restrict__ ain, const int8_t* __restrict__ qk,
    const float* __restrict__ bias, const float* __restrict__ wscales, int widx,
    const float* __restrict__ act_scales, int sin_idx, int sout_idx,
    uint8_t* __restrict__ aout)
{
    constexpr int RCO = 8;
    constexpr int CG = CO / RCO;
    constexpr int OH = H / 2, OW = W / 2;
    constexpr int PH = H + 2, PW = W + 2;
    constexpr int XW = NS * PH * PW * (CI / 4);
    static_assert(NS * OH * OW * CG == 256, "one job per thread");
    __shared__ alignas(16) uint32_t xin[XW];

    const int tid = threadIdx.x;
    const int n0 = blockIdx.x * NS;
    for (int i = tid; i < XW; i += 256) xin[i] = 0u;
    __syncthreads();
    const uint32_t* src = reinterpret_cast<const uint32_t*>(ain + (size_t)n0 * H * W * CI);
    constexpr int NLOAD = NS * H * W * (CI / 4);
    for (int i = tid; i < NLOAD; i += 256) {
        int c4 = i % (CI / 4);
        int w_ = (i / (CI / 4)) % W;
        int h_ = (i / (CI / 4 * W)) % H;
        int s_ = i / (CI / 4 * W * H);
        xin[((s_ * PH + h_ + 1) * PW + (w_ + 1)) * (CI / 4) + c4] = src[i];
    }
    __syncthreads();

    const int cg = tid % CG;
    const int pw = (tid / CG) % OW;
    const int ph = (tid / (CG * OW)) % OH;
    const int s  = tid / (CG * OW * OH);
    const int co0 = cg * RCO;

    int accK[2][2][RCO] = {};
    const uint32_t* xbase = xin + s * PH * PW * (CI / 4);
    const uint4* wglob = reinterpret_cast<const uint4*>(qk);

    #pragma unroll
    for (int kh = 0; kh < 3; ++kh)
        #pragma unroll
        for (int kw = 0; kw < 3; ++kw) {
            for (int c16 = 0; c16 < CI / 16; ++c16) {
                // ---- hoisted loads: 4 x-tiles (LDS) + RCO weight rows (global)
                uint4 xv[2][2];
                #pragma unroll
                for (int r = 0; r < 2; ++r)
                    #pragma unroll
                    for (int c = 0; c < 2; ++c) {
                        const int ih = 2 * ph + r + kh, iw = 2 * pw + c + kw;
                        xv[r][c] = *reinterpret_cast<const uint4*>(
                            xbase + (ih * PW + iw) * (CI / 4) + c16 * 4);
                    }
                uint4 wv[RCO];
                const int wo4 = (co0 * 9 + kh * 3 + kw) * (CI / 16) + c16;
                #pragma unroll
                for (int j = 0; j < RCO; ++j)
                    wv[j] = wglob[wo4 + j * 9 * (CI / 16)];
                // ---- compute: 32 independent dot16 chains ----
                #pragma unroll
                for (int j = 0; j < RCO; ++j)
                    #pragma unroll
                    for (int r = 0; r < 2; ++r)
                        #pragma unroll
                        for (int c = 0; c < 2; ++c)
                            accK[r][c][j] = dot16(xv[r][c], wv[j], accK[r][c][j]);
            }
        }

    const double sW  = (double)wscales[widx] / 7.0;
    const double saI = (double)act_scales[sin_idx];
    const double saO = (double)act_scales[sout_idx];
    uint32_t p0 = 0, p1 = 0;
    #pragma unroll
    for (int j = 0; j < RCO; ++j) {
        const double bj = (double)bias[co0 + j];
        int m = 0;
        #pragma unroll
        for (int r = 0; r < 2; ++r)
            #pragma unroll
            for (int c = 0; c < 2; ++c) {
                double y = ((double)accK[r][c][j] * sW) * saI + bj;
                double lv = fmin(fmax(rint(y / saO), 0.0), 15.0);
                int li = (int)lv;
                if (li > m) m = li;
            }
        if (j < 4) p0 |= (uint32_t)m << (8 * j);
        else       p1 |= (uint32_t)m << (8 * (j - 4));
    }
    uint8_t* dst = aout + (((size_t)(n0 + s) * OH * OW + ph * OW + pw) * CO + co0);
    uint2 pv; pv.x = p0; pv.y = p1;
    *reinterpret_cast<uint2*>(dst) = pv;
}

// ---------------------------------------------------------------------------
// FC1: (2048,256) u8 x (512,256) i8 -> f64 epilogue -> u8 levels (2048,512)
// block = 64 samples x 128 outputs, LDS-tiled
// ---------------------------------------------------------------------------
__global__ __launch_bounds__(256) void fc1_kernel(
    const uint8_t* __restrict__ a5, const int8_t* __restrict__ qk,
    const float* __restrict__ bias, const float* __restrict__ scales,
    const float* __restrict__ act, uint8_t* __restrict__ a6)
{
    __shared__ alignas(16) uint8_t at[64 * 256];
    __shared__ alignas(16) uint8_t wt[128 * 256];
    const int tid = threadIdx.x;
    const int n0 = (blockIdx.x >> 2) * 64;
    const int o0 = (blockIdx.x & 3) * 128;
    {
        const uint4* srca = reinterpret_cast<const uint4*>(a5 + (size_t)n0 * 256);
        uint4* dsta = reinterpret_cast<uint4*>(at);
        for (int i = tid; i < 64 * 256 / 16; i += 256) dsta[i] = srca[i];
        const uint4* srcw = reinterpret_cast<const uint4*>(qk + (size_t)o0 * 256);
        uint4* dstw = reinterpret_cast<uint4*>(wt);
        for (int i = tid; i < 128 * 256 / 16; i += 256) dstw[i] = srcw[i];
    }
    __syncthreads();
    const int ng = tid & 15, og = tid >> 4;
    const int nl = ng * 4, ol = og * 8;
    int acc[4][8] = {};
    const uint4* a4p = reinterpret_cast<const uint4*>(at);
    const uint4* w4p = reinterpret_cast<const uint4*>(wt);
    for (int c16 = 0; c16 < 16; ++c16) {
        uint4 av[4], wv[8];
        #pragma unroll
        for (int j = 0; j < 4; ++j) av[j] = a4p[(nl + j) * 16 + c16];
        #pragma unroll
        for (int k = 0; k < 8; ++k) wv[k] = w4p[(ol + k) * 16 + c16];
        #pragma unroll
        for (int j = 0; j < 4; ++j)
            #pragma unroll
            for (int k = 0; k < 8; ++k)
                acc[j][k] = dot16(av[j], wv[k], acc[j][k]);
    }
    const double sW = (double)scales[5] / 7.0;
    const double saI = (double)act[4], saO = (double)act[5];
    #pragma unroll
    for (int j = 0; j < 4; ++j) {
        uint32_t p0 = 0, p1 = 0;
        #pragma unroll
        for (int k = 0; k < 8; ++k) {
            double y = ((double)acc[j][k] * sW) * saI + (double)bias[o0 + ol + k];
            double lv = fmin(fmax(rint(y / saO), 0.0), 15.0);
            uint32_t li = (uint32_t)(int)lv;
            if (k < 4) p0 |= li << (8 * k); else p1 |= li << (8 * (k - 4));
        }
        uint2 pv; pv.x = p0; pv.y = p1;
        *reinterpret_cast<uint2*>(a6 + (size_t)(n0 + nl + j) * 512 + o0 + ol) = pv;
    }
}

// ---------------------------------------------------------------------------
// FC2 + quant_identity + softmax (all f64): one wave per sample
// ---------------------------------------------------------------------------
__global__ __launch_bounds__(256) void fc2_softmax_kernel(
    const uint8_t* __restrict__ a6, const int8_t* __restrict__ qk,
    const float* __restrict__ bias, const float* __restrict__ scales,
    const float* __restrict__ act, float* __restrict__ out)
{
    const int tid = threadIdx.x;
    const int wv = tid >> 6, lane = tid & 63;
    const int n = blockIdx.x * 4 + wv;
    const int o = lane;
    const uint32_t* arow = reinterpret_cast<const uint32_t*>(a6 + (size_t)n * 512);
    int acc = 0;
    if (o < 43) {
        const uint32_t* krow = reinterpret_cast<const uint32_t*>(qk + (size_t)o * 512);
        for (int c4 = 0; c4 < 128; ++c4) acc = dot4(arow[c4], krow[c4], acc);
    }
    const double sW = (double)scales[6] / 7.0;
    const double saI = (double)act[5], saO = (double)act[6];
    double z = -1.0e300;
    if (o < 43) {
        double y = ((double)acc * sW) * saI + (double)bias[o];
        double lv = fmin(fmax(rint(y / saO), -8.0), 7.0);
        z = lv * saO;
    }
    double m = z;
    #pragma unroll
    for (int off = 32; off; off >>= 1) m = fmax(m, __shfl_xor(m, off));
    double e = (o < 43) ? exp(z - m) : 0.0;
    double ssum = e;
    #pragma unroll
    for (int off = 32; off; off >>= 1) ssum += __shfl_xor(ssum, off);
    if (o < 43) out[(size_t)n * 43 + o] = (float)(e / ssum);
}

// ---------------------------------------------------------------------------
extern "C" void kernel_launch(void* const* d_in, const int* in_sizes, int n_in,
                              void* d_out, int out_size, void* d_ws, size_t ws_size,
                              hipStream_t stream) {
    const float* x   = (const float*)d_in[0];
    const float* w1  = (const float*)d_in[1];  const float* b1  = (const float*)d_in[2];
    const float* w2  = (const float*)d_in[3];  const float* b2  = (const float*)d_in[4];
    const float* w3  = (const float*)d_in[5];  const float* b3  = (const float*)d_in[6];
    const float* w4  = (const float*)d_in[7];  const float* b4  = (const float*)d_in[8];
    const float* w5  = (const float*)d_in[9];  const float* b5  = (const float*)d_in[10];
    const float* wf1 = (const float*)d_in[11]; const float* bf1 = (const float*)d_in[12];
    const float* wf2 = (const float*)d_in[13]; const float* bf2 = (const float*)d_in[14];
    const float* act = (const float*)d_in[15];
    float* out = (float*)d_out;

    uint8_t* wsb = (uint8_t*)d_ws;
    size_t off = 0;
    auto alloc = [&](size_t bytes) -> uint8_t* {
        uint8_t* r = wsb + off;
        off += (bytes + 255) & ~(size_t)255;
        return r;
    };
    float*   scales  = (float*)alloc(32 * 4);
    float*   partial = (float*)alloc(224 * 4);
    int8_t*  qk1  = (int8_t*)alloc(432);
    int8_t*  qk2  = (int8_t*)alloc(4608);
    int8_t*  qk3  = (int8_t*)alloc(18432);
    int8_t*  qk4  = (int8_t*)alloc(73728);
    int8_t*  qk5  = (int8_t*)alloc(294912);
    int8_t*  qkf1 = (int8_t*)alloc(131072);
    int8_t*  qkf2 = (int8_t*)alloc(22016);
    uint8_t* a1 = alloc((size_t)2048 * 16 * 16 * 16);
    uint8_t* a2 = alloc((size_t)2048 * 8 * 8 * 32);
    uint8_t* a3 = alloc((size_t)2048 * 4 * 4 * 64);
    uint8_t* a4 = alloc((size_t)2048 * 2 * 2 * 128);
    uint8_t* a5 = alloc((size_t)2048 * 256);
    uint8_t* a6 = alloc((size_t)2048 * 512);

    // --- weight quantization (3 dispatches) ---
    absmax_part_kernel<<<224, 256, 0, stream>>>(w1, w2, w3, w4, w5, wf1, wf2, partial);
    absmax_final_kernel<<<7, 64, 0, stream>>>(partial, scales);
    quantw_all_kernel<<<2130, 256, 0, stream>>>(
        w1, w2, w3, w4, w5, wf1, wf2,
        qk1, qk2, qk3, qk4, qk5, qkf1, qkf2, scales);

    // --- network ---
    conv1_kernel<<<2048, 256, 0, stream>>>(x, qk1, b1, scales, act, a1);
    convq_kernel<16, 32, 16, 16, 1><<<2048, 256, 0, stream>>>(a1, qk2, b2, scales, 1, act, 0, 1, a2);
    convq_kernel<32, 64, 8, 8, 2><<<1024, 256, 0, stream>>>(a2, qk3, b3, scales, 2, act, 1, 2, a3);
    convq_kernel<64, 128, 4, 4, 4><<<512, 256, 0, stream>>>(a3, qk4, b4, scales, 3, act, 2, 3, a4);
    convq_kernel<128, 256, 2, 2, 8><<<256, 256, 0, stream>>>(a4, qk5, b5, scales, 4, act, 3, 4, a5);
    fc1_kernel<<<128, 256, 0, stream>>>(a5, qkf1, bf1, scales, act, a6);
    fc2_softmax_kernel<<<512, 256, 0, stream>>>(a6, qkf2, bf2, scales, act, out);

    (void)in_sizes; (void)n_in; (void)out_size; (void)ws_size;
}

// Round 14
// 467.044 us; speedup vs baseline: 1.1002x; 1.0639x over previous
//
#include <hip/hip_runtime.h>
#include <hip/hip_bf16.h>
#include <cstdint>
#include <cmath>

// ---------------------------------------------------------------------------
// Quantized TSRNet forward — bit-faithful emulation of the np FLOAT64
// reference. Numerics contract (verified rounds 8/9/13: absmax 1.96e-5):
//   - s64 = (f64)absmax(w) / 7.0 ; k = clip(rint_f64(w/s64), -7, 7)
//   - conv2..5/fc: exact int32 dot4 accumulation; f64 epilogue.
//   - conv1: f64 accumulation of (f64)x * fl64(k*s64).
// Round-14: convq re-tiled to 512-thread blocks, RCO=4 (was 256/RCO=8).
// Evidence: rounds 8+13 both show convq at Occupancy ~10.4% (~4 waves/CU =
// one 256-thread block resident), VALUBusy ~28% -- latency fully exposed.
// Same grids, same LDS staging, same exact math; only the thread->channel
// mapping changes (VGPR ~132 -> ~95, waves/block 4 -> 8).
// ---------------------------------------------------------------------------

#if defined(__has_builtin)
#if __has_builtin(__builtin_amdgcn_sdot4)
#define HAVE_SDOT4 1
#endif
#endif

__device__ __forceinline__ int dot4(unsigned int a, unsigned int b, int c) {
#ifdef HAVE_SDOT4
    return __builtin_amdgcn_sdot4((int)a, (int)b, c, false);
#else
    #pragma unroll
    for (int k = 0; k < 4; ++k) {
        int av = (int)(signed char)((a >> (8 * k)) & 0xffu);
        int bv = (int)(signed char)((b >> (8 * k)) & 0xffu);
        c += av * bv;
    }
    return c;
#endif
}

__device__ __forceinline__ int dot16(uint4 a, uint4 b, int c) {
    c = dot4(a.x, b.x, c);
    c = dot4(a.y, b.y, c);
    c = dot4(a.z, b.z, c);
    c = dot4(a.w, b.w, c);
    return c;
}

// ---------------------------------------------------------------------------
// absmax per weight tensor; scales[t] = absmax (fp32, exact)
// ---------------------------------------------------------------------------
__global__ __launch_bounds__(256) void absmax_part_kernel(
    const float* __restrict__ w1, const float* __restrict__ w2,
    const float* __restrict__ w3, const float* __restrict__ w4,
    const float* __restrict__ w5, const float* __restrict__ wf1,
    const float* __restrict__ wf2, float* __restrict__ partial)
{
    const int t = blockIdx.x >> 5;
    const int k = blockIdx.x & 31;
    const float* p; int n;
    switch (t) {
        case 0: p = w1;  n = 432;    break;
        case 1: p = w2;  n = 4608;   break;
        case 2: p = w3;  n = 18432;  break;
        case 3: p = w4;  n = 73728;  break;
        case 4: p = w5;  n = 294912; break;
        case 5: p = wf1; n = 131072; break;
        default: p = wf2; n = 22016; break;
    }
    float m = 0.f;
    for (int i = k * 256 + threadIdx.x; i < n; i += 32 * 256)
        m = fmaxf(m, fabsf(p[i]));
    #pragma unroll
    for (int off = 32; off; off >>= 1) m = fmaxf(m, __shfl_xor(m, off));
    __shared__ float red[4];
    if ((threadIdx.x & 63) == 0) red[threadIdx.x >> 6] = m;
    __syncthreads();
    if (threadIdx.x == 0) {
        m = fmaxf(fmaxf(red[0], red[1]), fmaxf(red[2], red[3]));
        partial[blockIdx.x] = m;
    }
}

__global__ __launch_bounds__(64) void absmax_final_kernel(
    const float* __restrict__ partial, float* __restrict__ scales)
{
    const int t = blockIdx.x;
    float m = (threadIdx.x < 32) ? partial[t * 32 + threadIdx.x] : 0.f;
    #pragma unroll
    for (int off = 32; off; off >>= 1) m = fmaxf(m, __shfl_xor(m, off));
    if (threadIdx.x == 0) scales[t] = m;   // absmax; consumers divide by 7 in f64
}

// ---------------------------------------------------------------------------
// Fused weight quantization: all 7 tensors in one dispatch.
// conv tensors: OIHW -> OHWI permute; fc tensors: linear.
// f64 round-half-even, np-exact.
// ---------------------------------------------------------------------------
__global__ __launch_bounds__(256) void quantw_all_kernel(
    const float* __restrict__ w1, const float* __restrict__ w2,
    const float* __restrict__ w3, const float* __restrict__ w4,
    const float* __restrict__ w5, const float* __restrict__ wf1,
    const float* __restrict__ wf2,
    int8_t* __restrict__ q1, int8_t* __restrict__ q2,
    int8_t* __restrict__ q3, int8_t* __restrict__ q4,
    int8_t* __restrict__ q5, int8_t* __restrict__ qf1,
    int8_t* __restrict__ qf2,
    const float* __restrict__ scales)
{
    const int i = blockIdx.x * 256 + threadIdx.x;
    if (i >= 545200) return;
    int t, base, ci;
    const float* w; int8_t* q;
    if      (i < 432)    { t = 0; base = 0;      w = w1;  q = q1;  ci = 3;   }
    else if (i < 5040)   { t = 1; base = 432;    w = w2;  q = q2;  ci = 16;  }
    else if (i < 23472)  { t = 2; base = 5040;   w = w3;  q = q3;  ci = 32;  }
    else if (i < 97200)  { t = 3; base = 23472;  w = w4;  q = q4;  ci = 64;  }
    else if (i < 392112) { t = 4; base = 97200;  w = w5;  q = q5;  ci = 128; }
    else if (i < 523184) { t = 5; base = 392112; w = wf1; q = qf1; ci = 0;   }
    else                 { t = 6; base = 523184; w = wf2; q = qf2; ci = 0;   }
    const int li = i - base;
    const double s = (double)scales[t] / 7.0;
    const double kf = (s > 0.0) ? fmin(fmax(rint((double)w[li] / s), -7.0), 7.0) : 0.0;
    if (ci) {
        int kw = li % 3, kh = (li / 3) % 3, c = (li / 9) % ci, co = li / (9 * ci);
        q[((co * 3 + kh) * 3 + kw) * ci + c] = (int8_t)kf;
    } else {
        q[li] = (int8_t)kf;
    }
}

// ---------------------------------------------------------------------------
// Conv1: fp32 (2048,3,32,32) -> f64 acc with fl64(k*s64) weights -> quant_relu
// -> pool -> u8 levels NHWC (2048,16,16,16)
// ---------------------------------------------------------------------------
__global__ __launch_bounds__(256) void conv1_kernel(
    const float* __restrict__ x, const int8_t* __restrict__ qk,
    const float* __restrict__ bias, const float* __restrict__ wscales,
    const float* __restrict__ act_scales, uint8_t* __restrict__ a1)
{
    __shared__ alignas(16) float xin[3 * 34 * 34];
    const int tid = threadIdx.x;
    const int n = blockIdx.x;
    for (int i = tid; i < 3 * 34 * 34; i += 256) xin[i] = 0.f;
    __syncthreads();
    const float* xs = x + (size_t)n * 3072;
    for (int i = tid; i < 3072; i += 256) {
        int c = i >> 10, pix = i & 1023, h = pix >> 5, w = pix & 31;
        xin[c * 1156 + (h + 1) * 34 + (w + 1)] = xs[i];
    }
    __syncthreads();

    const double s64 = (double)wscales[0] / 7.0;
    const double sa = (double)act_scales[0];
    const int co = tid & 15, g = tid >> 4;
    double wr[27];
    #pragma unroll
    for (int k = 0; k < 27; ++k)
        wr[k] = (double)qk[co * 27 + k] * s64;          // fl64(k*s64) = np weight
    const double bco = (double)bias[co];
    uint8_t* outrow = a1 + (size_t)n * 4096;

    for (int t = 0; t < 16; ++t) {
        double acc[2][2] = {{0.0, 0.0}, {0.0, 0.0}};
        #pragma unroll
        for (int ci = 0; ci < 3; ++ci) {
            double xw[4][4];
            #pragma unroll
            for (int rr = 0; rr < 4; ++rr) {
                const int base = ci * 1156 + (2 * t + rr) * 34 + 2 * g;
                float2 v0 = *reinterpret_cast<const float2*>(&xin[base]);
                float2 v1 = *reinterpret_cast<const float2*>(&xin[base + 2]);
                xw[rr][0] = (double)v0.x; xw[rr][1] = (double)v0.y;
                xw[rr][2] = (double)v1.x; xw[rr][3] = (double)v1.y;
            }
            #pragma unroll
            for (int kh = 0; kh < 3; ++kh)
                #pragma unroll
                for (int kw = 0; kw < 3; ++kw) {
                    const double wv = wr[(kh * 3 + kw) * 3 + ci];
                    acc[0][0] += xw[kh][kw]         * wv;
                    acc[0][1] += xw[kh][kw + 1]     * wv;
                    acc[1][0] += xw[kh + 1][kw]     * wv;
                    acc[1][1] += xw[kh + 1][kw + 1] * wv;
                }
        }
        int m = 0;
        #pragma unroll
        for (int r = 0; r < 2; ++r)
            #pragma unroll
            for (int c = 0; c < 2; ++c) {
                double y = acc[r][c] + bco;
                double lv = fmin(fmax(rint(y / sa), 0.0), 15.0);
                int li = (int)lv;
                if (li > m) m = li;
            }
        outrow[(t * 16 + g) * 16 + co] = (uint8_t)m;
    }
}

// ---------------------------------------------------------------------------
// Int conv layers 2..5: exact int32 dot4 + f64 epilogue.
// 512-thread blocks, RCO=4: 8 waves/block, ~95 VGPR -> 2x+ resident waves
// vs the 256/RCO=8 variant (rounds 8+13: Occupancy 10.4%, VALUBusy 28%).
// Weights from GLOBAL (L1/L2-resident); per-(kh,kw,c16) loads hoisted.
// ---------------------------------------------------------------------------
template<int CI, int CO, int H, int W, int NS>
__global__ __launch_bounds__(512) void convq_kernel(
    const uint8_t* __restrict__ ain, const int8_t* __restrict__ qk,
    const float* __restrict__ bias, const float* __restrict__ wscales, int widx,
    const float* __restrict__ act_scales, int sin_idx, int sout_idx,
    uint8_t* __restrict__ aout)
{
    constexpr int T   = 512;
    constexpr int RCO = 4;
    constexpr int CG = CO / RCO;
    constexpr int OH = H / 2, OW = W / 2;
    constexpr int PH = H + 2, PW = W + 2;
    constexpr int XW = NS * PH * PW * (CI / 4);
    static_assert(NS * OH * OW * CG == T, "one job per thread");
    __shared__ alignas(16) uint32_t xin[XW];

    const int tid = threadIdx.x;
    const int n0 = blockIdx.x * NS;
    for (int i = tid; i < XW; i += T) xin[i] = 0u;
    __syncthreads();
    const uint32_t* src = reinterpret_cast<const uint32_t*>(ain + (size_t)n0 * H * W * CI);
    constexpr int NLOAD = NS * H * W * (CI / 4);
    for (int i = tid; i < NLOAD; i += T) {
        int c4 = i % (CI / 4);
        int w_ = (i / (CI / 4)) % W;
        int h_ = (i / (CI / 4 * W)) % H;
        int s_ = i / (CI / 4 * W * H);
        xin[((s_ * PH + h_ + 1) * PW + (w_ + 1)) * (CI / 4) + c4] = src[i];
    }
    __syncthreads();

    const int cg = tid % CG;
    const int pw = (tid / CG) % OW;
    const int ph = (tid / (CG * OW)) % OH;
    const int s  = tid / (CG * OW * OH);
    const int co0 = cg * RCO;

    int accK[2][2][RCO] = {};
    const uint32_t* xbase = xin + s * PH * PW * (CI / 4);
    const uint4* wglob = reinterpret_cast<const uint4*>(qk);

    #pragma unroll
    for (int kh = 0; kh < 3; ++kh)
        #pragma unroll
        for (int kw = 0; kw < 3; ++kw) {
            for (int c16 = 0; c16 < CI / 16; ++c16) {
                // ---- hoisted loads: 4 x-tiles (LDS) + RCO weight rows (global)
                uint4 xv[2][2];
                #pragma unroll
                for (int r = 0; r < 2; ++r)
                    #pragma unroll
                    for (int c = 0; c < 2; ++c) {
                        const int ih = 2 * ph + r + kh, iw = 2 * pw + c + kw;
                        xv[r][c] = *reinterpret_cast<const uint4*>(
                            xbase + (ih * PW + iw) * (CI / 4) + c16 * 4);
                    }
                uint4 wv[RCO];
                const int wo4 = (co0 * 9 + kh * 3 + kw) * (CI / 16) + c16;
                #pragma unroll
                for (int j = 0; j < RCO; ++j)
                    wv[j] = wglob[wo4 + j * 9 * (CI / 16)];
                // ---- compute: 16 independent dot16 chains ----
                #pragma unroll
                for (int j = 0; j < RCO; ++j)
                    #pragma unroll
                    for (int r = 0; r < 2; ++r)
                        #pragma unroll
                        for (int c = 0; c < 2; ++c)
                            accK[r][c][j] = dot16(xv[r][c], wv[j], accK[r][c][j]);
            }
        }

    const double sW  = (double)wscales[widx] / 7.0;
    const double saI = (double)act_scales[sin_idx];
    const double saO = (double)act_scales[sout_idx];
    uint32_t p0 = 0;
    #pragma unroll
    for (int j = 0; j < RCO; ++j) {
        const double bj = (double)bias[co0 + j];
        int m = 0;
        #pragma unroll
        for (int r = 0; r < 2; ++r)
            #pragma unroll
            for (int c = 0; c < 2; ++c) {
                double y = ((double)accK[r][c][j] * sW) * saI + bj;
                double lv = fmin(fmax(rint(y / saO), 0.0), 15.0);
                int li = (int)lv;
                if (li > m) m = li;
            }
        p0 |= (uint32_t)m << (8 * j);
    }
    uint8_t* dst = aout + (((size_t)(n0 + s) * OH * OW + ph * OW + pw) * CO + co0);
    *reinterpret_cast<uint32_t*>(dst) = p0;
}

// ---------------------------------------------------------------------------
// FC1: (2048,256) u8 x (512,256) i8 -> f64 epilogue -> u8 levels (2048,512)
// block = 64 samples x 128 outputs, LDS-tiled
// ---------------------------------------------------------------------------
__global__ __launch_bounds__(256) void fc1_kernel(
    const uint8_t* __restrict__ a5, const int8_t* __restrict__ qk,
    const float* __restrict__ bias, const float* __restrict__ scales,
    const float* __restrict__ act, uint8_t* __restrict__ a6)
{
    __shared__ alignas(16) uint8_t at[64 * 256];
    __shared__ alignas(16) uint8_t wt[128 * 256];
    const int tid = threadIdx.x;
    const int n0 = (blockIdx.x >> 2) * 64;
    const int o0 = (blockIdx.x & 3) * 128;
    {
        const uint4* srca = reinterpret_cast<const uint4*>(a5 + (size_t)n0 * 256);
        uint4* dsta = reinterpret_cast<uint4*>(at);
        for (int i = tid; i < 64 * 256 / 16; i += 256) dsta[i] = srca[i];
        const uint4* srcw = reinterpret_cast<const uint4*>(qk + (size_t)o0 * 256);
        uint4* dstw = reinterpret_cast<uint4*>(wt);
        for (int i = tid; i < 128 * 256 / 16; i += 256) dstw[i] = srcw[i];
    }
    __syncthreads();
    const int ng = tid & 15, og = tid >> 4;
    const int nl = ng * 4, ol = og * 8;
    int acc[4][8] = {};
    const uint4* a4p = reinterpret_cast<const uint4*>(at);
    const uint4* w4p = reinterpret_cast<const uint4*>(wt);
    for (int c16 = 0; c16 < 16; ++c16) {
        uint4 av[4], wv[8];
        #pragma unroll
        for (int j = 0; j < 4; ++j) av[j] = a4p[(nl + j) * 16 + c16];
        #pragma unroll
        for (int k = 0; k < 8; ++k) wv[k] = w4p[(ol + k) * 16 + c16];
        #pragma unroll
        for (int j = 0; j < 4; ++j)
            #pragma unroll
            for (int k = 0; k < 8; ++k)
                acc[j][k] = dot16(av[j], wv[k], acc[j][k]);
    }
    const double sW = (double)scales[5] / 7.0;
    const double saI = (double)act[4], saO = (double)act[5];
    #pragma unroll
    for (int j = 0; j < 4; ++j) {
        uint32_t p0 = 0, p1 = 0;
        #pragma unroll
        for (int k = 0; k < 8; ++k) {
            double y = ((double)acc[j][k] * sW) * saI + (double)bias[o0 + ol + k];
            double lv = fmin(fmax(rint(y / saO), 0.0), 15.0);
            uint32_t li = (uint32_t)(int)lv;
            if (k < 4) p0 |= li << (8 * k); else p1 |= li << (8 * (k - 4));
        }
        uint2 pv; pv.x = p0; pv.y = p1;
        *reinterpret_cast<uint2*>(a6 + (size_t)(n0 + nl + j) * 512 + o0 + ol) = pv;
    }
}

// ---------------------------------------------------------------------------
// FC2 + quant_identity + softmax (all f64): one wave per sample
// ---------------------------------------------------------------------------
__global__ __launch_bounds__(256) void fc2_softmax_kernel(
    const uint8_t* __restrict__ a6, const int8_t* __restrict__ qk,
    const float* __restrict__ bias, const float* __restrict__ scales,
    const float* __restrict__ act, float* __restrict__ out)
{
    const int tid = threadIdx.x;
    const int wv = tid >> 6, lane = tid & 63;
    const int n = blockIdx.x * 4 + wv;
    const int o = lane;
    const uint32_t* arow = reinterpret_cast<const uint32_t*>(a6 + (size_t)n * 512);
    int acc = 0;
    if (o < 43) {
        const uint32_t* krow = reinterpret_cast<const uint32_t*>(qk + (size_t)o * 512);
        for (int c4 = 0; c4 < 128; ++c4) acc = dot4(arow[c4], krow[c4], acc);
    }
    const double sW = (double)scales[6] / 7.0;
    const double saI = (double)act[5], saO = (double)act[6];
    double z = -1.0e300;
    if (o < 43) {
        double y = ((double)acc * sW) * saI + (double)bias[o];
        double lv = fmin(fmax(rint(y / saO), -8.0), 7.0);
        z = lv * saO;
    }
    double m = z;
    #pragma unroll
    for (int off = 32; off; off >>= 1) m = fmax(m, __shfl_xor(m, off));
    double e = (o < 43) ? exp(z - m) : 0.0;
    double ssum = e;
    #pragma unroll
    for (int off = 32; off; off >>= 1) ssum += __shfl_xor(ssum, off);
    if (o < 43) out[(size_t)n * 43 + o] = (float)(e / ssum);
}

// ---------------------------------------------------------------------------
extern "C" void kernel_launch(void* const* d_in, const int* in_sizes, int n_in,
                              void* d_out, int out_size, void* d_ws, size_t ws_size,
                              hipStream_t stream) {
    const float* x   = (const float*)d_in[0];
    const float* w1  = (const float*)d_in[1];  const float* b1  = (const float*)d_in[2];
    const float* w2  = (const float*)d_in[3];  const float* b2  = (const float*)d_in[4];
    const float* w3  = (const float*)d_in[5];  const float* b3  = (const float*)d_in[6];
    const float* w4  = (const float*)d_in[7];  const float* b4  = (const float*)d_in[8];
    const float* w5  = (const float*)d_in[9];  const float* b5  = (const float*)d_in[10];
    const float* wf1 = (const float*)d_in[11]; const float* bf1 = (const float*)d_in[12];
    const float* wf2 = (const float*)d_in[13]; const float* bf2 = (const float*)d_in[14];
    const float* act = (const float*)d_in[15];
    float* out = (float*)d_out;

    uint8_t* wsb = (uint8_t*)d_ws;
    size_t off = 0;
    auto alloc = [&](size_t bytes) -> uint8_t* {
        uint8_t* r = wsb + off;
        off += (bytes + 255) & ~(size_t)255;
        return r;
    };
    float*   scales  = (float*)alloc(32 * 4);
    float*   partial = (float*)alloc(224 * 4);
    int8_t*  qk1  = (int8_t*)alloc(432);
    int8_t*  qk2  = (int8_t*)alloc(4608);
    int8_t*  qk3  = (int8_t*)alloc(18432);
    int8_t*  qk4  = (int8_t*)alloc(73728);
    int8_t*  qk5  = (int8_t*)alloc(294912);
    int8_t*  qkf1 = (int8_t*)alloc(131072);
    int8_t*  qkf2 = (int8_t*)alloc(22016);
    uint8_t* a1 = alloc((size_t)2048 * 16 * 16 * 16);
    uint8_t* a2 = alloc((size_t)2048 * 8 * 8 * 32);
    uint8_t* a3 = alloc((size_t)2048 * 4 * 4 * 64);
    uint8_t* a4 = alloc((size_t)2048 * 2 * 2 * 128);
    uint8_t* a5 = alloc((size_t)2048 * 256);
    uint8_t* a6 = alloc((size_t)2048 * 512);

    // --- weight quantization (3 dispatches) ---
    absmax_part_kernel<<<224, 256, 0, stream>>>(w1, w2, w3, w4, w5, wf1, wf2, partial);
    absmax_final_kernel<<<7, 64, 0, stream>>>(partial, scales);
    quantw_all_kernel<<<2130, 256, 0, stream>>>(
        w1, w2, w3, w4, w5, wf1, wf2,
        qk1, qk2, qk3, qk4, qk5, qkf1, qkf2, scales);

    // --- network ---
    conv1_kernel<<<2048, 256, 0, stream>>>(x, qk1, b1, scales, act, a1);
    convq_kernel<16, 32, 16, 16, 1><<<2048, 512, 0, stream>>>(a1, qk2, b2, scales, 1, act, 0, 1, a2);
    convq_kernel<32, 64, 8, 8, 2><<<1024, 512, 0, stream>>>(a2, qk3, b3, scales, 2, act, 1, 2, a3);
    convq_kernel<64, 128, 4, 4, 4><<<512, 512, 0, stream>>>(a3, qk4, b4, scales, 3, act, 2, 3, a4);
    convq_kernel<128, 256, 2, 2, 8><<<256, 512, 0, stream>>>(a4, qk5, b5, scales, 4, act, 3, 4, a5);
    fc1_kernel<<<128, 256, 0, stream>>>(a5, qkf1, bf1, scales, act, a6);
    fc2_softmax_kernel<<<512, 256, 0, stream>>>(a6, qkf2, bf2, scales, act, out);

    (void)in_sizes; (void)n_in; (void)out_size; (void)ws_size;
}